// Round 6
// baseline (259.041 us; speedup 1.0000x reference)
//
#include <hip/hip_runtime.h>

#define BINS 10
#define ALPHA 0.75f

constexpr int NB    = 4096;   // pass-1 blocks: 2 generations of resident blocks
constexpr int NT    = 256;    // threads per block (4 waves)
constexpr int ITERS = 4;      // float4 steps per thread (NB*NT*ITERS*4 == 2^24)

typedef float v4f __attribute__((ext_vector_type(4)));
typedef int   v4i __attribute__((ext_vector_type(4)));

// Cumulative bin thresholds on u = diff*(2t-1):
//   g = sigmoid(-u); g >= k/10  <=>  u <= L_k = ln((10-k)/k)
// bin(g) = #{k: u <= L_k}; per-bin recovered by differencing in finalize.
__device__ constexpr float LTH[9] = {
    2.19722458f,  1.38629436f,  0.847297861f, 0.405465108f, 0.0f,
   -0.405465108f, -0.847297861f, -1.38629436f, -2.19722458f};

#define GHM_PROC(AX, BX, TX) do {                                    \
    float diff = (AX) - (BX);                                        \
    float nd   = -diff;                                              \
    bool  tt   = (TX) != 0;                                          \
    float u    = tt ? diff : nd;                                     \
    float loss = tt ? fmaxf(nd, 0.0f) : 0.0f;                        \
    cls[0] += loss;                                                  \
    _Pragma("unroll")                                                \
    for (int k = 1; k < BINS; ++k) {                                 \
      bool p = (u <= LTH[k - 1]);                                    \
      cls[k] += p ? loss : 0.0f;                                     \
      cnt[k] += (unsigned int)p;                                     \
    }                                                                \
  } while (0)

#define GHM_PROC4(AV, BV, TV) do {                                   \
    GHM_PROC((AV).x, (BV).x, (TV).x);                                \
    GHM_PROC((AV).y, (BV).y, (TV).y);                                \
    GHM_PROC((AV).z, (BV).z, (TV).z);                                \
    GHM_PROC((AV).w, (BV).w, (TV).w);                                \
  } while (0)

// Nontemporal (streaming, evict-first) 16-B loads: inputs are consumed once.
__device__ __forceinline__ v4f nt4f(const v4f* p) { return __builtin_nontemporal_load(p); }
__device__ __forceinline__ v4i nt4i(const v4i* p) { return __builtin_nontemporal_load(p); }

// Pass 1: depth-2 register pipeline (round-4 structure, best measured at
// 77 us) + NT loads + backfill-friendly grid (NB = 2x resident capacity so
// finished blocks are immediately replaced — round-4's 44% occupancy was
// tail idling with NB == capacity). Per-bin cumulative {count, loss-sum} in
// registers (static indexing), wave/LDS reduce, ONE atomicAdd per bin per
// block (double loss, u32 count).
__global__ __launch_bounds__(NT) void ghm_pass1(
    const float* __restrict__ o1f, const float* __restrict__ o2f,
    const int* __restrict__ tgt, double* __restrict__ gls,
    unsigned int* __restrict__ gcnt, int n)
{
  const v4f* o1 = reinterpret_cast<const v4f*>(o1f);
  const v4f* o2 = reinterpret_cast<const v4f*>(o2f);
  const v4i* tg = reinterpret_cast<const v4i*>(tgt);

  float        cls[BINS];
  unsigned int cnt[BINS];
#pragma unroll
  for (int b = 0; b < BINS; ++b) { cls[b] = 0.0f; cnt[b] = 0u; }

  if (n == NB * NT * ITERS * 4 && gridDim.x == NB) {
    // Block owns NT*ITERS consecutive float4s; thread strides by NT (coalesced).
    const int base = blockIdx.x * (NT * ITERS) + threadIdx.x;
    v4f a0 = nt4f(o1 + base);      v4f b0 = nt4f(o2 + base);      v4i t0 = nt4i(tg + base);
    v4f a1 = nt4f(o1 + base + NT); v4f b1 = nt4f(o2 + base + NT); v4i t1 = nt4i(tg + base + NT);
#pragma unroll
    for (int k = 0; k < ITERS - 2; ++k) {
      v4f a2 = nt4f(o1 + base + (k + 2) * NT);
      v4f b2 = nt4f(o2 + base + (k + 2) * NT);
      v4i t2 = nt4i(tg + base + (k + 2) * NT);
      __builtin_amdgcn_sched_barrier(0);   // prefetch stays ABOVE compute
      GHM_PROC4(a0, b0, t0);
      a0 = a1; b0 = b1; t0 = t1;
      a1 = a2; b1 = b2; t1 = t2;
    }
    GHM_PROC4(a0, b0, t0);
    GHM_PROC4(a1, b1, t1);
  } else {
    // Generic grid-stride fallback (any n / grid).
    const int tid = blockIdx.x * NT + threadIdx.x;
    const int stride = gridDim.x * NT;
    const int n4 = n >> 2;
    for (int i = tid; i < n4; i += stride) {
      v4f a  = o1[i];
      v4f bb = o2[i];
      v4i t  = tg[i];
      GHM_PROC4(a, bb, t);
    }
    if (tid == 0) {
      for (int i = n4 * 4; i < n; ++i) GHM_PROC(o1f[i], o2f[i], tgt[i]);
    }
  }

  // Wave shuffle reduce -> cross-wave LDS reduce -> one atomic per bin.
  const int lane = threadIdx.x & 63;
  const int wv   = threadIdx.x >> 6;
  __shared__ float        s_ls[NT / 64][BINS];
  __shared__ unsigned int s_c [NT / 64][BINS];
#pragma unroll
  for (int b = 0; b < BINS; ++b) {
    float v = cls[b];
    unsigned int cv = cnt[b];
#pragma unroll
    for (int off = 32; off >= 1; off >>= 1) {
      v  += __shfl_down(v, off, 64);
      cv += __shfl_down(cv, off, 64);
    }
    if (lane == 0) { s_ls[wv][b] = v; s_c[wv][b] = cv; }
  }
  __syncthreads();
  if (threadIdx.x < BINS) {
    float v = 0.0f; unsigned int cv = 0u;
#pragma unroll
    for (int w = 0; w < NT / 64; ++w) { v += s_ls[w][threadIdx.x]; cv += s_c[w][threadIdx.x]; }
    atomicAdd(&gls[threadIdx.x], (double)v);
    if (cv) atomicAdd(&gcnt[threadIdx.x], cv);
  }
}

// Finalize: difference cumulative sums, apply w[b] = max((f32)count,1)^-0.75
// (matching reference's f32 cast of counts), write the scalar mean. Runs in a
// separate dispatch => pass-1 atomics are globally visible (no stale-L2 risk).
__global__ void ghm_final(const double* __restrict__ gls,
                          const unsigned int* __restrict__ gcnt,
                          float* __restrict__ out, int n)
{
  if (threadIdx.x == 0) {
    double             CLS[BINS + 1];
    unsigned long long CC [BINS + 1];
#pragma unroll
    for (int b = 0; b < BINS; ++b) { CLS[b] = gls[b]; CC[b] = gcnt[b]; }
    CLS[BINS] = 0.0; CC[BINS] = 0ull;
    CC[0] = (unsigned long long)n;   // cumulative count at k=0 = all elements

    double total = 0.0;
#pragma unroll
    for (int b = 0; b < BINS; ++b) {
      double lsb            = CLS[b] - CLS[b + 1];
      unsigned long long cb = CC[b] - CC[b + 1];
      float cf  = (float)cb;           // counts.astype(float32)
      float tot = fmaxf(cf, 1.0f);     // clip(counts, 1.0)
      float wgt = powf(tot, -ALPHA);   // tot ** -0.75
      total += lsb * (double)wgt;
    }
    out[0] = (float)(total / (double)n);
  }
}

extern "C" void kernel_launch(void* const* d_in, const int* in_sizes, int n_in,
                              void* d_out, int out_size, void* d_ws, size_t ws_size,
                              hipStream_t stream) {
  const float* o1  = (const float*)d_in[0];
  const float* o2  = (const float*)d_in[1];
  const int*   tgt = (const int*)d_in[2];
  float* out = (float*)d_out;
  const int n = in_sizes[0];

  // ws layout: double gls[10] (80 B) then u32 gcnt[10] (40 B). Harness poisons
  // ws with 0xAA each call; zero it inside the graph (memsetAsync is capturable).
  double*       gls  = (double*)d_ws;
  unsigned int* gcnt = (unsigned int*)((char*)d_ws + BINS * sizeof(double));
  hipMemsetAsync(d_ws, 0, BINS * (sizeof(double) + sizeof(unsigned int)), stream);

  ghm_pass1<<<NB, NT, 0, stream>>>(o1, o2, tgt, gls, gcnt, n);
  ghm_final<<<1, 64, 0, stream>>>(gls, gcnt, out, n);
}

// Round 7
// 220.223 us; speedup vs baseline: 1.1763x; 1.1763x over previous
//
#include <hip/hip_runtime.h>

#define BINS 10
#define ALPHA 0.75f

constexpr int NB    = 2048;   // pass-1 blocks (= resident capacity, uniform work)
constexpr int NT    = 256;    // threads per block (4 waves)
constexpr int ITERS = 8;      // float4 steps per thread (NB*NT*ITERS*4 == 2^24)
constexpr int NT2   = 1024;   // pass-2 threads (single block, 16 waves)

typedef float v4f __attribute__((ext_vector_type(4)));
typedef int   v4i __attribute__((ext_vector_type(4)));

// Cumulative bin thresholds on u = diff*(2t-1):
//   g = sigmoid(-u); g >= k/10  <=>  u <= L_k = ln((10-k)/k)
// bin(g) = #{k: u <= L_k}; per-bin recovered by differencing in pass 2.
// (Replaces exp/rcp in the hot loop; measured VALUBusy 35% -> 23%, R3.)
__device__ constexpr float LTH[9] = {
    2.19722458f,  1.38629436f,  0.847297861f, 0.405465108f, 0.0f,
   -0.405465108f, -0.847297861f, -1.38629436f, -2.19722458f};

#define GHM_PROC(AX, BX, TX) do {                                    \
    float diff = (AX) - (BX);                                        \
    float nd   = -diff;                                              \
    bool  tt   = (TX) != 0;                                          \
    float u    = tt ? diff : nd;                                     \
    float loss = tt ? fmaxf(nd, 0.0f) : 0.0f;                        \
    cls[0] += loss;                                                  \
    _Pragma("unroll")                                                \
    for (int k = 1; k < BINS; ++k) {                                 \
      bool p = (u <= LTH[k - 1]);                                    \
      cls[k] += p ? loss : 0.0f;                                     \
      cnt[k] += (unsigned int)p;                                     \
    }                                                                \
  } while (0)

#define GHM_PROC4(AV, BV, TV) do {                                   \
    GHM_PROC((AV).x, (BV).x, (TV).x);                                \
    GHM_PROC((AV).y, (BV).y, (TV).y);                                \
    GHM_PROC((AV).z, (BV).z, (TV).z);                                \
    GHM_PROC((AV).w, (BV).w, (TV).w);                                \
  } while (0)

// Pass 1: fused elementwise + cumulative per-bin {count, loss-sum}.
// Plain fully-unrolled fixed-trip loop, compiler-scheduled (measured best:
// 77-80 us across R2/R4; sched_barrier pinning, LDS-DMA staging, and NT
// hints all measured neutral-to-worse, R3-R6). Delivered read BW here is
// ~84% of the per-CU vector-L1 miss-path ceiling (~5.1 B/cyc/CU, from
// m13's copy read side) — structure-independent across 5 variants.
__global__ __launch_bounds__(NT) void ghm_pass1(
    const float* __restrict__ o1f, const float* __restrict__ o2f,
    const int* __restrict__ tgt, float* __restrict__ lsum_part,
    unsigned int* __restrict__ cnt_part, int n)
{
  const v4f* o1 = reinterpret_cast<const v4f*>(o1f);
  const v4f* o2 = reinterpret_cast<const v4f*>(o2f);
  const v4i* tg = reinterpret_cast<const v4i*>(tgt);

  float        cls[BINS];   // cls[0]=total loss; cls[k] cumulative loss-sum
  unsigned int cnt[BINS];   // cnt[k], k>=1 cumulative counts; cnt[0] stays 0
#pragma unroll
  for (int b = 0; b < BINS; ++b) { cls[b] = 0.0f; cnt[b] = 0u; }

  if (n == NB * NT * ITERS * 4 && gridDim.x == NB) {
    // Block owns NT*ITERS consecutive float4s; thread strides by NT (coalesced).
    const int base = blockIdx.x * (NT * ITERS) + threadIdx.x;
#pragma unroll
    for (int k = 0; k < ITERS; ++k) {
      v4f a = o1[base + k * NT];
      v4f b = o2[base + k * NT];
      v4i t = tg[base + k * NT];
      GHM_PROC4(a, b, t);
    }
  } else {
    // Generic grid-stride fallback (any n / grid).
    const int tid = blockIdx.x * NT + threadIdx.x;
    const int stride = gridDim.x * NT;
    const int n4 = n >> 2;
    for (int i = tid; i < n4; i += stride) {
      v4f a  = o1[i];
      v4f bb = o2[i];
      v4i t  = tg[i];
      GHM_PROC4(a, bb, t);
    }
    if (tid == 0) {
      for (int i = n4 * 4; i < n; ++i) GHM_PROC(o1f[i], o2f[i], tgt[i]);
    }
  }

  // Wave shuffle reduce -> cross-wave LDS reduce -> one deterministic partial
  // per block (no atomics). Partials TRANSPOSED [BINS][nb]: pass-2 reads
  // contiguous per bin.
  const int lane = threadIdx.x & 63;
  const int wv   = threadIdx.x >> 6;
  __shared__ float        s_ls[NT / 64][BINS];
  __shared__ unsigned int s_c [NT / 64][BINS];
#pragma unroll
  for (int b = 0; b < BINS; ++b) {
    float v = cls[b];
    unsigned int cv = cnt[b];
#pragma unroll
    for (int off = 32; off >= 1; off >>= 1) {
      v  += __shfl_down(v, off, 64);
      cv += __shfl_down(cv, off, 64);
    }
    if (lane == 0) { s_ls[wv][b] = v; s_c[wv][b] = cv; }
  }
  __syncthreads();
  if (threadIdx.x < BINS) {
    float v = 0.0f; unsigned int cv = 0u;
#pragma unroll
    for (int w = 0; w < NT / 64; ++w) { v += s_ls[w][threadIdx.x]; cv += s_c[w][threadIdx.x]; }
    lsum_part[threadIdx.x * gridDim.x + blockIdx.x] = v;
    cnt_part [threadIdx.x * gridDim.x + blockIdx.x] = cv;
  }
}

// Pass 2: one wide block reduces [BINS][nparts] cumulative partials in double
// (coalesced contiguous reads per bin), differences cumulative->per-bin,
// applies w[b] = max((f32)cnt,1)^-0.75 (reference's f32 cast), writes mean.
__global__ __launch_bounds__(NT2) void ghm_pass2(
    const float* __restrict__ lsum_part, const unsigned int* __restrict__ cnt_part,
    float* __restrict__ out, int nparts, int n)
{
  double             cls[BINS];
  unsigned long long cc [BINS];
#pragma unroll
  for (int b = 0; b < BINS; ++b) { cls[b] = 0.0; cc[b] = 0ull; }

  for (int i = threadIdx.x; i < nparts; i += NT2) {
#pragma unroll
    for (int b = 0; b < BINS; ++b) {
      cls[b] += (double)lsum_part[b * nparts + i];
      cc[b]  += (unsigned long long)cnt_part[b * nparts + i];
    }
  }

  const int lane = threadIdx.x & 63;
  const int wv   = threadIdx.x >> 6;
  __shared__ double             s_ls[NT2 / 64][BINS];
  __shared__ unsigned long long s_c [NT2 / 64][BINS];
#pragma unroll
  for (int b = 0; b < BINS; ++b) {
    double v = cls[b];
    unsigned long long cv = cc[b];
#pragma unroll
    for (int off = 32; off >= 1; off >>= 1) {
      v  += __shfl_down(v, off, 64);
      cv += __shfl_down(cv, off, 64);
    }
    if (lane == 0) { s_ls[wv][b] = v; s_c[wv][b] = cv; }
  }
  __syncthreads();
  if (threadIdx.x == 0) {
    double             CLS[BINS + 1];
    unsigned long long CC [BINS + 1];
#pragma unroll
    for (int b = 0; b < BINS; ++b) {
      double lv = 0.0; unsigned long long cv = 0ull;
#pragma unroll
      for (int w = 0; w < NT2 / 64; ++w) { lv += s_ls[w][b]; cv += s_c[w][b]; }
      CLS[b] = lv; CC[b] = cv;
    }
    CLS[BINS] = 0.0; CC[BINS] = 0ull;
    CC[0] = (unsigned long long)n;   // cumulative count at k=0 = all elements

    double total = 0.0;
#pragma unroll
    for (int b = 0; b < BINS; ++b) {
      double lsb            = CLS[b] - CLS[b + 1];
      unsigned long long cb = CC[b] - CC[b + 1];
      float cf  = (float)cb;           // counts.astype(float32)
      float tot = fmaxf(cf, 1.0f);     // clip(counts, 1.0)
      float wgt = powf(tot, -ALPHA);   // tot ** -0.75
      total += lsb * (double)wgt;
    }
    out[0] = (float)(total / (double)n);
  }
}

extern "C" void kernel_launch(void* const* d_in, const int* in_sizes, int n_in,
                              void* d_out, int out_size, void* d_ws, size_t ws_size,
                              hipStream_t stream) {
  const float* o1  = (const float*)d_in[0];
  const float* o2  = (const float*)d_in[1];
  const int*   tgt = (const int*)d_in[2];
  float* out = (float*)d_out;
  const int n = in_sizes[0];

  // ws layout: [BINS][nb] f32 cumulative loss partials, then [BINS][nb] u32
  // cumulative count partials. Every slot written by pass1 (no zero-init).
  int nb = NB;
  size_t need = (size_t)nb * BINS * (sizeof(float) + sizeof(unsigned int));
  while (nb > 1 && need > ws_size) { nb >>= 1; need >>= 1; }  // safety only
  float* lsum_part = (float*)d_ws;
  unsigned int* cnt_part = (unsigned int*)((char*)d_ws + (size_t)nb * BINS * sizeof(float));

  ghm_pass1<<<nb, NT, 0, stream>>>(o1, o2, tgt, lsum_part, cnt_part, n);
  ghm_pass2<<<1, NT2, 0, stream>>>(lsum_part, cnt_part, out, nb, n);
}